// Round 2
// baseline (2529.326 us; speedup 1.0000x reference)
//
#include <hip/hip_runtime.h>
#include <stdint.h>
#include <stddef.h>

// ---------------------------------------------------------------------------
// CounterfactualDiffusion: 50 sequential steps of a 4-layer MLP (258->512->512
// ->512->128) + DDPM update with JAX-threefry noise, batch 8192.
// Single persistent kernel: 256 WGs x 512 threads, each WG owns 32 rows for
// the whole 50-step loop. bf16 MFMA 16x16x32, f32 accum, x-state f32 in LDS.
// Weights pre-transposed to [N][K] bf16 by a prep kernel so B-fragments are
// contiguous 16B loads (B[k=quad*8+j][n=lane&15] needs k-contiguous storage).
// Noise: JAX partitionable threefry (default since jax 0.4.36):
//   bits[i] = o0 ^ o1, (o0,o1) = threefry2x32(fold_in(key(42),t), 0, i)
// ---------------------------------------------------------------------------

typedef __bf16 bf16;
typedef __bf16 bf16x8 __attribute__((ext_vector_type(8)));
typedef float  floatx4 __attribute__((ext_vector_type(4)));

#define NSTEPS    50
#define WG_ROWS   32
#define XB_STRIDE 136   // 128 cols + pad (keeps 16B align: 136=17*8)
#define H_STRIDE  520   // 512 cols + pad (520=65*8)
#define XF_STRIDE 132

__device__ __forceinline__ uint32_t rotl32(uint32_t x, int r) {
  return (x << r) | (x >> (32 - r));
}

// JAX threefry-2x32, 20 rounds (jax/_src/prng.py key schedule).
__device__ __forceinline__ void threefry2x32(uint32_t k0, uint32_t k1,
                                             uint32_t x0, uint32_t x1,
                                             uint32_t& o0, uint32_t& o1) {
  uint32_t k2 = k0 ^ k1 ^ 0x1BD11BDAu;
  x0 += k0; x1 += k1;
#define TF_R(R) { x0 += x1; x1 = rotl32(x1, R); x1 ^= x0; }
  TF_R(13) TF_R(15) TF_R(26) TF_R(6)
  x0 += k1; x1 += k2 + 1u;
  TF_R(17) TF_R(29) TF_R(16) TF_R(24)
  x0 += k2; x1 += k0 + 2u;
  TF_R(13) TF_R(15) TF_R(26) TF_R(6)
  x0 += k0; x1 += k1 + 3u;
  TF_R(17) TF_R(29) TF_R(16) TF_R(24)
  x0 += k1; x1 += k2 + 4u;
  TF_R(13) TF_R(15) TF_R(26) TF_R(6)
  x0 += k2; x1 += k0 + 5u;
#undef TF_R
  o0 = x0; o1 = x1;
}

// XLA's ErfInv32 (Giles 2010) — matches lax.erf_inv on f32.
__device__ __forceinline__ float erfinv_xla(float x) {
  float w = -log1pf(-x * x);
  float p;
  if (w < 5.0f) {
    w -= 2.5f;
    p = 2.81022636e-08f;
    p = fmaf(p, w, 3.43273939e-07f);
    p = fmaf(p, w, -3.5233877e-06f);
    p = fmaf(p, w, -4.39150654e-06f);
    p = fmaf(p, w, 0.00021858087f);
    p = fmaf(p, w, -0.00125372503f);
    p = fmaf(p, w, -0.00417768164f);
    p = fmaf(p, w, 0.246640727f);
    p = fmaf(p, w, 1.50140941f);
  } else {
    w = sqrtf(w) - 3.0f;
    p = -0.000200214257f;
    p = fmaf(p, w, 0.000100950558f);
    p = fmaf(p, w, 0.00134934322f);
    p = fmaf(p, w, -0.00367342844f);
    p = fmaf(p, w, 0.00573950773f);
    p = fmaf(p, w, -0.0076224613f);
    p = fmaf(p, w, 0.00943887047f);
    p = fmaf(p, w, 1.00167406f);
    p = fmaf(p, w, 2.83297682f);
  }
  return p * x;
}

__device__ __forceinline__ float gelu_exact(float x) {
  return 0.5f * x * (1.0f + erff(x * 0.7071067811865475f));
}

// MFMA 16x16x32 bf16 micro-GEMM: M=32 (2 tiles), N = NT*16, K = KSTEPS*32.
// A in LDS row-major [32][ASTRIDE] (lane holds A[m=lane&15][k=quad*8+j]).
// B in global, pre-transposed [N][BSTRIDE] so B[k][n] is k-contiguous at row n.
template<int KSTEPS, int NT, int ASTRIDE, int BSTRIDE>
__device__ __forceinline__ void gemm_block(const bf16* __restrict__ A_lds,
                                           const bf16* __restrict__ B_gbl,
                                           int lane, floatx4 (&acc)[2][NT]) {
  const int m = lane & 15, q = lane >> 4;
  const bf16* a0 = A_lds + m * ASTRIDE + q * 8;
  const bf16* b0 = B_gbl + m * BSTRIDE + q * 8;
#pragma unroll 2
  for (int ks = 0; ks < KSTEPS; ++ks) {
    bf16x8 af0 = *(const bf16x8*)(a0 + ks * 32);
    bf16x8 af1 = *(const bf16x8*)(a0 + 16 * ASTRIDE + ks * 32);
#pragma unroll
    for (int nt = 0; nt < NT; ++nt) {
      bf16x8 bfr = *(const bf16x8*)(b0 + nt * 16 * BSTRIDE + ks * 32);
      acc[0][nt] = __builtin_amdgcn_mfma_f32_16x16x32_bf16(af0, bfr, acc[0][nt], 0, 0, 0);
      acc[1][nt] = __builtin_amdgcn_mfma_f32_16x16x32_bf16(af1, bfr, acc[1][nt], 0, 0, 0);
    }
  }
}

// ---------------------------------------------------------------------------
// Prep: weights f32->bf16 transposed [N][K]; per-step L1 bias (b1 + t_emb*W1row256
// + target*W1row257); step constants; folded threefry keys.
// ---------------------------------------------------------------------------
__global__ void diff_prep(const float* __restrict__ W1, const float* __restrict__ b1,
                          const float* __restrict__ W2, const float* __restrict__ W3,
                          const float* __restrict__ W4, const int* __restrict__ tsurv,
                          bf16* __restrict__ w1t, bf16* __restrict__ w2t,
                          bf16* __restrict__ w3t, bf16* __restrict__ w4t,
                          float* __restrict__ eb1, uint32_t* __restrict__ fk,
                          float* __restrict__ cst) {
  const int tid = blockIdx.x * blockDim.x + threadIdx.x;
  const int nth = gridDim.x * blockDim.x;
  for (int i = tid; i < 512 * 256; i += nth) {          // W1T[n][k]=W1[k][n], k<256
    int n = i >> 8, k = i & 255;
    w1t[i] = (bf16)W1[k * 512 + n];
  }
  for (int i = tid; i < 512 * 512; i += nth) {          // W2T, W3T
    int n = i >> 9, k = i & 511;
    w2t[i] = (bf16)W2[k * 512 + n];
    w3t[i] = (bf16)W3[k * 512 + n];
  }
  for (int i = tid; i < 128 * 512; i += nth) {          // W4T[n][k]=W4[k][n]
    int n = i >> 9, k = i & 511;
    w4t[i] = (bf16)W4[k * 128 + n];
  }
  const float tgt = (tsurv[0] != 0) ? 0.0f : 1.0f;
  for (int i = tid; i < NSTEPS * 512; i += nth) {       // per-step layer-1 bias
    int t = i >> 9, n = i & 511;
    eb1[i] = b1[n] + ((float)t / 50.0f) * W1[256 * 512 + n] + tgt * W1[257 * 512 + n];
  }
  if (tid == 0) {                                       // step consts + folded keys
    float ac = 1.0f;
    for (int t = 0; t < NSTEPS; ++t) {
      float beta  = 1e-4f + (0.02f - 1e-4f) * ((float)t / 49.0f);
      float alpha = 1.0f - beta;
      ac *= alpha;
      cst[t]           = beta / sqrtf(1.0f - ac);   // c1
      cst[NSTEPS + t]  = 1.0f / sqrtf(alpha);       // c2
      cst[2*NSTEPS + t]= sqrtf(beta);               // c3
      uint32_t o0, o1;
      threefry2x32(0u, 42u, 0u, (uint32_t)t, o0, o1);  // fold_in(key(42), t)
      fk[t] = o0; fk[NSTEPS + t] = o1;
    }
  }
}

// ---------------------------------------------------------------------------
// Main persistent kernel. 256 WGs x 512 threads (8 waves, wave w owns an
// N-slice). Single h LDS buffer (sync after reads, before overwrite) keeps
// static LDS at 58.9KB. cond@W1[128:256] projection lives in 32 VGPRs/wave.
// ---------------------------------------------------------------------------
__global__ __launch_bounds__(512, 2) void diff_main(
    const float* __restrict__ cond, const float* __restrict__ xinit,
    const bf16* __restrict__ w1t, const bf16* __restrict__ w2t,
    const bf16* __restrict__ w3t, const bf16* __restrict__ w4t,
    const float* __restrict__ eb1, const float* __restrict__ b2,
    const float* __restrict__ b3, const float* __restrict__ b4,
    const uint32_t* __restrict__ fk, const float* __restrict__ cst,
    float* __restrict__ out) {
  __shared__ bf16 xb[WG_ROWS * XB_STRIDE];   // x as bf16 (layer-1 A operand)
  __shared__ bf16 hb[WG_ROWS * H_STRIDE];    // shared hidden buffer (h1/h2/h3)
  __shared__ float xf[WG_ROWS * XF_STRIDE];  // x state, f32

  const int tid  = threadIdx.x;
  const int wave = tid >> 6;
  const int lane = tid & 63;
  const int m = lane & 15, q = lane >> 4;
  const int r0 = blockIdx.x * WG_ROWS;

  // ---- init: stage x_init (f32+bf16) and condition (bf16, into hb) ----
  {
    const int row = tid >> 4;
    const int c8  = (tid & 15) * 8;
    const float4* xi = (const float4*)(xinit + (size_t)(r0 + row) * 128 + c8);
    const float4* cd = (const float4*)(cond  + (size_t)(r0 + row) * 128 + c8);
    float4 a = xi[0], b = xi[1], c = cd[0], d = cd[1];
    *(float4*)(xf + row * XF_STRIDE + c8)     = a;
    *(float4*)(xf + row * XF_STRIDE + c8 + 4) = b;
    float xv[8] = {a.x, a.y, a.z, a.w, b.x, b.y, b.z, b.w};
    float cv[8] = {c.x, c.y, c.z, c.w, d.x, d.y, d.z, d.w};
    bf16x8 x8, c8v;
#pragma unroll
    for (int j = 0; j < 8; ++j) { x8[j] = (bf16)xv[j]; c8v[j] = (bf16)cv[j]; }
    *(bf16x8*)(xb + row * XB_STRIDE + c8) = x8;
    *(bf16x8*)(hb + row * H_STRIDE  + c8) = c8v;
  }
  __syncthreads();

  // ---- cproj = cond @ W1[128:256,:]  -> stays in registers (same C-layout
  //      the layer-1 accumulator will use) ----
  floatx4 cpr[2][4] = {};
  gemm_block<4, 4, H_STRIDE, 256>(hb, w1t + (wave * 64) * 256 + 128, lane, cpr);
  __syncthreads();  // all reads of hb(cond) done; hb free

  for (int t = NSTEPS - 1; t >= 0; --t) {
    // ---- layer 1: h1 = gelu(x@W1[:128] + cproj + eb1[t]) ----
    {
      floatx4 acc[2][4] = {};
      gemm_block<4, 4, XB_STRIDE, 256>(xb, w1t + (wave * 64) * 256, lane, acc);
      const float* ebt = eb1 + t * 512;
#pragma unroll
      for (int nt = 0; nt < 4; ++nt) {
        const int col = wave * 64 + nt * 16 + m;
        const float bb = ebt[col];
#pragma unroll
        for (int mt = 0; mt < 2; ++mt)
#pragma unroll
          for (int r = 0; r < 4; ++r) {
            const int row = mt * 16 + q * 4 + r;
            float v = acc[mt][nt][r] + cpr[mt][nt][r] + bb;
            hb[row * H_STRIDE + col] = (bf16)gelu_exact(v);
          }
      }
    }
    __syncthreads();

    // ---- layer 2: h2 = gelu(h1@W2 + b2)  (read hb, sync, overwrite hb) ----
    {
      floatx4 acc[2][4] = {};
      gemm_block<16, 4, H_STRIDE, 512>(hb, w2t + (wave * 64) * 512, lane, acc);
      __syncthreads();
#pragma unroll
      for (int nt = 0; nt < 4; ++nt) {
        const int col = wave * 64 + nt * 16 + m;
        const float bb = b2[col];
#pragma unroll
        for (int mt = 0; mt < 2; ++mt)
#pragma unroll
          for (int r = 0; r < 4; ++r) {
            const int row = mt * 16 + q * 4 + r;
            hb[row * H_STRIDE + col] = (bf16)gelu_exact(acc[mt][nt][r] + bb);
          }
      }
    }
    __syncthreads();

    // ---- layer 3: h3 = gelu(h2@W3 + b3) ----
    {
      floatx4 acc[2][4] = {};
      gemm_block<16, 4, H_STRIDE, 512>(hb, w3t + (wave * 64) * 512, lane, acc);
      __syncthreads();
#pragma unroll
      for (int nt = 0; nt < 4; ++nt) {
        const int col = wave * 64 + nt * 16 + m;
        const float bb = b3[col];
#pragma unroll
        for (int mt = 0; mt < 2; ++mt)
#pragma unroll
          for (int r = 0; r < 4; ++r) {
            const int row = mt * 16 + q * 4 + r;
            hb[row * H_STRIDE + col] = (bf16)gelu_exact(acc[mt][nt][r] + bb);
          }
      }
    }
    __syncthreads();

    // ---- layer 4 + DDPM update (wave owns cols [wave*16, wave*16+16)) ----
    {
      floatx4 acc[2][1] = {};
      gemm_block<16, 1, H_STRIDE, 512>(hb, w4t + (wave * 16) * 512, lane, acc);
      const float c1 = cst[t], c2 = cst[NSTEPS + t], c3 = cst[2 * NSTEPS + t];
      const uint32_t fk0 = fk[t], fk1 = fk[NSTEPS + t];
      const int col = wave * 16 + m;
      const float bb = b4[col];
#pragma unroll
      for (int mt = 0; mt < 2; ++mt)
#pragma unroll
        for (int r = 0; r < 4; ++r) {
          const int row = mt * 16 + q * 4 + r;
          float np = acc[mt][0][r] + bb;
          float z = 0.0f;
          if (t > 0) {
            // JAX partitionable random_bits (32-bit):
            //   counts = iota(u64); (o0,o1)=threefry(key, hi32, lo32); bits=o0^o1
            uint32_t gidx = (uint32_t)(r0 + row) * 128u + (uint32_t)col;
            uint32_t o0, o1;
            threefry2x32(fk0, fk1, 0u, gidx, o0, o1);
            uint32_t bits = o0 ^ o1;
            float f01 = __uint_as_float((bits >> 9) | 0x3F800000u) - 1.0f;
            float u = f01 * 2.0f + (-0.99999994f);   // (hi-lo) rounds to exactly 2.0f
            u = fmaxf(-0.99999994f, u);
            z = 1.4142135381698608f * erfinv_xla(u);
          }
          float xo = xf[row * XF_STRIDE + col];
          float xn = (xo - c1 * np) * c2 + c3 * z;
          xf[row * XF_STRIDE + col] = xn;
          xb[row * XB_STRIDE + col] = (bf16)xn;
        }
    }
    __syncthreads();
  }

  // ---- writeout ----
  {
    const int row = tid >> 4;
    const int c8  = (tid & 15) * 8;
    float4 a = *(float4*)(xf + row * XF_STRIDE + c8);
    float4 b = *(float4*)(xf + row * XF_STRIDE + c8 + 4);
    float4* op = (float4*)(out + (size_t)(r0 + row) * 128 + c8);
    op[0] = a; op[1] = b;
  }
}

// ---------------------------------------------------------------------------
extern "C" void kernel_launch(void* const* d_in, const int* in_sizes, int n_in,
                              void* d_out, int out_size, void* d_ws, size_t ws_size,
                              hipStream_t stream) {
  const float* cond  = (const float*)d_in[0];
  const float* xinit = (const float*)d_in[1];
  const float* W1 = (const float*)d_in[2];
  const float* b1 = (const float*)d_in[3];
  const float* W2 = (const float*)d_in[4];
  const float* b2 = (const float*)d_in[5];
  const float* W3 = (const float*)d_in[6];
  const float* b3 = (const float*)d_in[7];
  const float* W4 = (const float*)d_in[8];
  const float* b4 = (const float*)d_in[9];
  const int* tsurv = (const int*)d_in[10];

  char* ws = (char*)d_ws;                    // ~1.48 MB used
  bf16* w1t = (bf16*)(ws + 0);               // 512*256*2 = 262144
  bf16* w2t = (bf16*)(ws + 262144);          // 512*512*2 = 524288
  bf16* w3t = (bf16*)(ws + 786432);          // 524288
  bf16* w4t = (bf16*)(ws + 1310720);         // 128*512*2 = 131072
  float* eb1 = (float*)(ws + 1441792);       // 50*512*4 = 102400
  uint32_t* fkp = (uint32_t*)(ws + 1544192); // 100*4
  float* cstp = (float*)(ws + 1544704);      // 150*4

  diff_prep<<<1024, 256, 0, stream>>>(W1, b1, W2, W3, W4, tsurv,
                                      w1t, w2t, w3t, w4t, eb1, fkp, cstp);
  diff_main<<<256, 512, 0, stream>>>(cond, xinit, w1t, w2t, w3t, w4t,
                                     eb1, b2, b3, b4, fkp, cstp, (float*)d_out);
}